// Round 4
// baseline (4433.812 us; speedup 1.0000x reference)
//
#include <hip/hip_runtime.h>
#include <math.h>

// SPINN forward, fp32 (argmax trajectory sensitivity forbids bf16/f16).
// PERSISTENT kernel v2 — fence-free coherence:
//  - cross-block data (X, gpart, lpart, TH, dec) via RELAXED AGENT atomics (sc1:
//    bypass L1/L2, coherent at LLC). NO acquire/release fences -> no L2 invalidation
//    (round-2's 48MB/step refetch storm came from per-phase acquire fences).
//  - weights (W1T/W2T/W3T/buffers/b*) normal cached loads -> L2-resident all 64 steps.
//  - stack is block-private by construction (persistent block <-> fixed (row,j-slice))
//    -> normal cached access, zero coherence traffic.
//  - barriers: 2-level counter trees; arrive = s_waitcnt(0)+relaxed fetch_add (stores
//    are sc1 so vmcnt-retired == LLC-visible); wait = relaxed poll + s_sleep.
//  - grid 512 = 2 blocks/CU guaranteed (launch_bounds(256,2), LDS 58.5KB) -> no deadlock.
// Per step: A [224 gates tiles (K=1792,N=1024,GSPLIT=14,n0=64w) || 256 lstm5 tiles
// (K=1024,N=2560,LSPLIT=8,n0=80w)] -> bar1(gates) -> M [128 row-blocks: gather+LSTM
// (tc,sp,bl in REGISTERS across steps)+logits+argmax+dec] -> bar2(lstm5+M) ->
// C [512 = 16 rowgroups x 32 j-slices: LDS-staged track-GEMM + TreeLSTM node + stack
// + next-X] -> bar3.

#define B_ 128
#define CAP 42
#define XW 2048   // X row: [buf_h 0:512 | s1_h 512:1024 | s2_h 1024:1536 | th_old 1536:1792 | pad]
#define GSPLIT 14
#define LSPLIT 8
#define NSTEP 64

__device__ __forceinline__ float sigm(float x) { return 1.f / (1.f + expf(-x)); }

// ---- coherent (LLC-level) access helpers: relaxed agent atomics -> sc1, no fences ----
__device__ __forceinline__ float cload(const float* p) {
    return __hip_atomic_load(p, __ATOMIC_RELAXED, __HIP_MEMORY_SCOPE_AGENT);
}
__device__ __forceinline__ void cstore(float* p, float v) {
    __hip_atomic_store(p, v, __ATOMIC_RELAXED, __HIP_MEMORY_SCOPE_AGENT);
}
__device__ __forceinline__ int cloadi(const int* p) {
    return __hip_atomic_load(p, __ATOMIC_RELAXED, __HIP_MEMORY_SCOPE_AGENT);
}
__device__ __forceinline__ void cstorei(int* p, int v) {
    __hip_atomic_store(p, v, __ATOMIC_RELAXED, __HIP_MEMORY_SCOPE_AGENT);
}
__device__ __forceinline__ float2 cload2(const float* p) {
    unsigned long long u = __hip_atomic_load((const unsigned long long*)p,
                                             __ATOMIC_RELAXED, __HIP_MEMORY_SCOPE_AGENT);
    union { unsigned long long u; float2 f; } c; c.u = u; return c.f;
}
__device__ __forceinline__ void cstore2(float* p, float x, float y) {
    union { unsigned long long u; float2 f; } c; c.f = make_float2(x, y);
    __hip_atomic_store((unsigned long long*)p, c.u, __ATOMIC_RELAXED, __HIP_MEMORY_SCOPE_AGENT);
}

// ---- tree barrier primitives (called by tid==0 only, after __syncthreads) ----
__device__ __forceinline__ void bar_arrive(unsigned* grp, unsigned quota, unsigned* root, unsigned ep) {
    asm volatile("" ::: "memory");
    __builtin_amdgcn_s_waitcnt(0);
    unsigned v = __hip_atomic_fetch_add(grp, 1u, __ATOMIC_RELAXED, __HIP_MEMORY_SCOPE_AGENT) + 1u;
    if (v == quota * ep)
        __hip_atomic_fetch_add(root, 1u, __ATOMIC_RELAXED, __HIP_MEMORY_SCOPE_AGENT);
}
__device__ __forceinline__ void bar_wait(unsigned* root, unsigned target) {
    while (__hip_atomic_load(root, __ATOMIC_RELAXED, __HIP_MEMORY_SCOPE_AGENT) < target)
        __builtin_amdgcn_s_sleep(1);
    asm volatile("" ::: "memory");
}

// ---------------- repack weights ----------------
__global__ void k_repack(const float* __restrict__ W_ih, const float* __restrict__ W_hh,
                         const float* __restrict__ W_left, const float* __restrict__ W_right,
                         const float* __restrict__ W_track, const float* __restrict__ b_ih,
                         const float* __restrict__ b_hh,
                         float* __restrict__ W1T, float* __restrict__ W2T,
                         float* __restrict__ W3T, float* __restrict__ b1) {
    size_t idx = (size_t)blockIdx.x * 256 + threadIdx.x;
    const size_t n1 = 1792ull * 1024ull;
    const size_t n2 = 1024ull * 2560ull;
    const size_t n3 = 256ull * 2560ull;
    if (idx < n1) {
        int k = (int)(idx >> 10), n = (int)(idx & 1023);
        W1T[idx] = (k < 1536) ? W_ih[(size_t)n * 1536 + k] : W_hh[(size_t)n * 256 + (k - 1536)];
    } else if (idx < n1 + n2) {
        size_t r = idx - n1;
        int k = (int)(r / 2560), n = (int)(r % 2560);
        W2T[r] = (k < 512) ? W_right[(size_t)n * 512 + k] : W_left[(size_t)n * 512 + (k - 512)];
    } else if (idx < n1 + n2 + n3) {
        size_t r = idx - n1 - n2;
        int k = (int)(r / 2560), n = (int)(r % 2560);
        W3T[r] = W_track[(size_t)n * 256 + k];
    } else if (idx < n1 + n2 + n3 + 1024) {
        int i = (int)(idx - n1 - n2 - n3);
        b1[i] = b_ih[i] + b_hh[i];
    }
}

// ---------------- init state ----------------
__global__ void k_init(const float* __restrict__ buffers, float* __restrict__ stack,
                       float* __restrict__ X, unsigned* __restrict__ cnt) {
    int b = blockIdx.x, t = threadIdx.x;
    const float* b0 = buffers + (size_t)b * 40 * 1024;
    const float* btop = b0 + 39 * 1024;
    float* stk = stack + (size_t)b * CAP * 1024;
    for (int j = t; j < 1024; j += 256) { stk[j] = b0[j]; stk[1024 + j] = b0[j]; }
    float* Xb = X + (size_t)b * XW;
    for (int j = t; j < 512; j += 256) {
        Xb[j] = btop[j]; Xb[512 + j] = b0[j]; Xb[1024 + j] = b0[j];
    }
    Xb[1536 + t] = 0.f;
    if (b == 0) { for (int i = t; i < 1024; i += 256) cnt[i] = 0u; }
}

// ---------------- persistent kernel ----------------
// counters: root1=cnt[0], root2=cnt[16], root3=cnt[32];
// g1 = cnt[64+gid*16] (7 grps x32), g2a = cnt[192+gid*16] (8x32 lstm5),
// g2b = cnt[320+gid*16] (8x16 M), g3 = cnt[448+gid*16] (8x64).
__global__ __launch_bounds__(256, 2) void k_spinn(
        float* __restrict__ X,
        const float* __restrict__ W1T, const float* __restrict__ W2T,
        const float* __restrict__ W3T,
        float* __restrict__ gpart, float* __restrict__ lpart,
        const float* __restrict__ b1, const float* __restrict__ b_left,
        const float* __restrict__ W_trans, const float* __restrict__ b_trans,
        const float* __restrict__ buffers, float* __restrict__ stack,
        float* __restrict__ TH, int* __restrict__ dec,
        float* __restrict__ out, unsigned* cnt) {
    const int bid = blockIdx.x, tid = threadIdx.x;
    __shared__ float As[32][132];       // 16.9 KB
    __shared__ float Ws[32][84];        // 10.75 KB
    __shared__ float w_s[5184];         // 20.7 KB  [u(16)][g(5)][kk(64)] stride 324
    __shared__ float th_s[8 * 260];     // 8.3 KB
    __shared__ float shg[128 * 6];      // 3.1 KB
    __shared__ float redw[4][4];
    __shared__ float lgs[4];
    __shared__ int   dec_s[8];

    const bool is_g = bid < 224;
    const bool is_l = (bid >= 224) && (bid < 480);
    const bool is_m = (bid >= 224) && (bid < 352);

    int n0g = 0, k0g = 0, n0l = 0, k0l = 0;
    if (is_g) { k0g = (bid >> 4) * 128; n0g = (bid & 15) * 64; }
    if (is_l) { int tI = bid - 224; k0l = (tI >> 5) * 128; n0l = (tI & 31) * 80; }
    const int tm = tid >> 4, tn = tid & 15;

    // M persistent register state
    const int mrow = bid - 224;
    float tc_reg = 0.f; int sp = 2, bl = 40;
    float wtr0 = 0, wtr1 = 0, wtr2 = 0, wtr3 = 0, b1v0 = 0, b1v1 = 0, b1v2 = 0, b1v3 = 0;
    if (is_m) {
        wtr0 = W_trans[tid]; wtr1 = W_trans[256 + tid];
        wtr2 = W_trans[512 + tid]; wtr3 = W_trans[768 + tid];
        b1v0 = b1[tid]; b1v1 = b1[256 + tid]; b1v2 = b1[512 + tid]; b1v3 = b1[768 + tid];
    }
    // C role params
    const int r0 = (bid >> 5) * 8;
    const int jqb = (bid & 31) * 16;
    const int kh = tid >> 7, rl = (tid >> 4) & 7, jgc = tid & 15;

    for (int s = 0; s < NSTEP; s++) {
        const unsigned ep = (unsigned)(s + 1);
        // ================= phase A =================
        if (is_g) {
            float acc[8][4];
#pragma unroll
            for (int i = 0; i < 8; i++) { acc[i][0] = 0; acc[i][1] = 0; acc[i][2] = 0; acc[i][3] = 0; }
            for (int ki = 0; ki < 128; ki += 32) {
                const int kb = k0g + ki;
                __syncthreads();
                {   int m = tid >> 1, c8 = (tid & 1) * 16;
                    const float* srcA = X + (size_t)m * XW + kb + c8;
#pragma unroll
                    for (int jj = 0; jj < 8; jj++) {
                        float2 v = cload2(srcA + jj * 2);
                        As[c8 + jj * 2][m] = v.x; As[c8 + jj * 2 + 1][m] = v.y;
                    }
                }
                {   int kk = tid >> 3, c = (tid & 7) * 8;
                    const float4* src = (const float4*)(W1T + (size_t)(kb + kk) * 1024 + n0g + c);
                    float4* dst = (float4*)(&Ws[kk][c]);
                    dst[0] = src[0]; dst[1] = src[1];
                }
                __syncthreads();
#pragma unroll 4
                for (int kk = 0; kk < 32; kk++) {
                    float a[8], w[4];
                    *(float4*)&a[0] = *(const float4*)&As[kk][tm * 4];
                    *(float4*)&a[4] = *(const float4*)&As[kk][64 + tm * 4];
                    *(float4*)&w[0] = *(const float4*)&Ws[kk][tn * 4];
#pragma unroll
                    for (int i = 0; i < 8; i++)
#pragma unroll
                        for (int j = 0; j < 4; j++) acc[i][j] += a[i] * w[j];
                }
            }
            float* base = gpart + (size_t)(bid >> 4) * 131072 + n0g + tn * 4;
#pragma unroll
            for (int i = 0; i < 8; i++) {
                int m = (i < 4) ? (tm * 4 + i) : (64 + tm * 4 + (i - 4));
                float* p = base + (size_t)m * 1024;
                cstore2(p, acc[i][0], acc[i][1]);
                cstore2(p + 2, acc[i][2], acc[i][3]);
            }
            __syncthreads();
            if (tid == 0) bar_arrive(cnt + 64 + (bid >> 5) * 16, 32u, cnt + 0, ep);
        } else if (is_l && s < 63) {
            float acc[8][5];
#pragma unroll
            for (int i = 0; i < 8; i++) { acc[i][0]=0; acc[i][1]=0; acc[i][2]=0; acc[i][3]=0; acc[i][4]=0; }
            for (int ki = 0; ki < 128; ki += 32) {
                const int kb = k0l + ki;
                __syncthreads();
                {   int m = tid >> 1, c8 = (tid & 1) * 16;
                    const float* srcA = X + (size_t)m * XW + 512 + kb + c8;
#pragma unroll
                    for (int jj = 0; jj < 8; jj++) {
                        float2 v = cload2(srcA + jj * 2);
                        As[c8 + jj * 2][m] = v.x; As[c8 + jj * 2 + 1][m] = v.y;
                    }
                }
#pragma unroll
                for (int i = 0; i < 3; i++) {
                    int F = i * 256 + tid;
                    if (F < 640) {
                        int kk = F / 20, u4 = F % 20;
                        const float4* src = (const float4*)(W2T + (size_t)(kb + kk) * 2560 + n0l + u4 * 4);
                        *(float4*)&Ws[kk][u4 * 4] = *src;
                    }
                }
                __syncthreads();
#pragma unroll 2
                for (int kk = 0; kk < 32; kk++) {
                    float a[8];
                    *(float4*)&a[0] = *(const float4*)&As[kk][tm * 4];
                    *(float4*)&a[4] = *(const float4*)&As[kk][64 + tm * 4];
                    float4 w4 = *(const float4*)&Ws[kk][tn * 4];
                    float w5 = Ws[kk][64 + tn];
#pragma unroll
                    for (int i = 0; i < 8; i++) {
                        acc[i][0] += a[i] * w4.x; acc[i][1] += a[i] * w4.y;
                        acc[i][2] += a[i] * w4.z; acc[i][3] += a[i] * w4.w;
                        acc[i][4] += a[i] * w5;
                    }
                }
            }
            float* base = lpart + (size_t)((bid - 224) >> 5) * 327680 + n0l;
#pragma unroll
            for (int i = 0; i < 8; i++) {
                int m = (i < 4) ? (tm * 4 + i) : (64 + tm * 4 + (i - 4));
                float* p = base + (size_t)m * 2560 + tn * 4;
                cstore2(p, acc[i][0], acc[i][1]);
                cstore2(p + 2, acc[i][2], acc[i][3]);
                cstore(base + (size_t)m * 2560 + 64 + tn, acc[i][4]);
            }
            __syncthreads();
            if (tid == 0) bar_arrive(cnt + 192 + ((bid - 224) >> 5) * 16, 32u, cnt + 16, ep);
        }
        // ================= phase M =================
        if (is_m) {
            if (tid == 0) bar_wait(cnt + 0, 7u * ep);
            __syncthreads();
            const float* gp = gpart + (size_t)mrow * 1024;
            float gi = b1v0, gf = b1v1, gg = b1v2, go = b1v3;
#pragma unroll
            for (int kc = 0; kc < GSPLIT; kc++) {
                const float* p = gp + (size_t)kc * 131072;
                gi += cload(p + tid); gf += cload(p + 256 + tid);
                gg += cload(p + 512 + tid); go += cload(p + 768 + tid);
            }
            float tcn = sigm(gf) * tc_reg + sigm(gi) * tanhf(gg);
            float thn = sigm(go) * tanhf(tcn);
            tc_reg = tcn;
            if (s < 63) {
                cstore(X + (size_t)mrow * XW + 1536 + tid, thn);
                cstore(TH + (size_t)mrow * 256 + tid, thn);
            }
            float v0 = thn * wtr0, v1 = thn * wtr1, v2 = thn * wtr2, v3 = thn * wtr3;
#pragma unroll
            for (int off = 32; off > 0; off >>= 1) {
                v0 += __shfl_down(v0, off); v1 += __shfl_down(v1, off);
                v2 += __shfl_down(v2, off); v3 += __shfl_down(v3, off);
            }
            if ((tid & 63) == 0) {
                int w = tid >> 6;
                redw[w][0] = v0; redw[w][1] = v1; redw[w][2] = v2; redw[w][3] = v3;
            }
            __syncthreads();
            if (tid == 0) {
#pragma unroll
                for (int l = 0; l < 4; l++)
                    lgs[l] = redw[0][l] + redw[1][l] + redw[2][l] + redw[3][l] + b_trans[l];
            }
            __syncthreads();
            float l0 = lgs[0], l1 = lgs[1], l2 = lgs[2], l3 = lgs[3];
            int tr = 0; float best = l0;
            if (l1 > best) { best = l1; tr = 1; }
            if (l2 > best) { best = l2; tr = 2; }
            if (l3 > best) { best = l3; tr = 3; }
            bool shv = (tr == 3) && (bl > 2);
            bool rdv = (tr == 2) && (sp > 3);
            if (tid < 4) out[(size_t)s * 512 + mrow * 4 + tid] = lgs[tid];
            if (tid == 0 && s < 63)
                cstorei(dec + mrow, sp | (bl << 6) | (shv ? 4096 : 0) | (rdv ? 8192 : 0));
            sp += (shv ? 1 : 0) - (rdv ? 1 : 0);
            bl -= (shv ? 1 : 0);
            __syncthreads();
            if (tid == 0) bar_arrive(cnt + 320 + ((bid - 224) >> 4) * 16, 16u, cnt + 16, ep);
        }
        if (s == 63) break;
        // ================= phase C (all 512 blocks) =================
        if (tid == 0) bar_wait(cnt + 16, 16u * ep);
        __syncthreads();
        {   // stage th_s (8 rows x 256, stride 260)
            int rr = tid >> 5, c0 = (tid & 31) * 8;
            const float* src = TH + (size_t)(r0 + rr) * 256 + c0;
            float* dst = &th_s[rr * 260 + c0];
#pragma unroll
            for (int i = 0; i < 4; i++) { float2 v = cload2(src + i * 2); dst[i * 2] = v.x; dst[i * 2 + 1] = v.y; }
        }
        if (tid < 8) dec_s[tid] = cloadi(dec + r0 + tid);
        float ac0 = 0, ac1 = 0, ac2 = 0, ac3 = 0, ac4 = 0;
        for (int c = 0; c < 4; c++) {
#pragma unroll
            for (int i = 0; i < 5; i++) {       // stage w_s chunk c (64 k x 80 cols)
                int F = i * 256 + tid;
                int kk = F / 20, rem = F % 20, g = rem >> 2, u4 = rem & 3;
                float4 v = *(const float4*)(W3T + (size_t)(c * 64 + kk) * 2560 + g * 512 + jqb + u4 * 4);
                float* d = &w_s[(u4 * 4) * 324 + g * 64 + kk];
                d[0] = v.x; d[324] = v.y; d[648] = v.z; d[972] = v.w;
            }
            __syncthreads();
#pragma unroll
            for (int kk4 = 0; kk4 < 8; kk4++) {
                int kk = kh * 32 + kk4 * 4;
                float4 t4 = *(const float4*)&th_s[rl * 260 + c * 64 + kk];
                float4 w;
                w = *(const float4*)&w_s[jgc * 324 + 0 * 64 + kk];
                ac0 += t4.x * w.x + t4.y * w.y + t4.z * w.z + t4.w * w.w;
                w = *(const float4*)&w_s[jgc * 324 + 1 * 64 + kk];
                ac1 += t4.x * w.x + t4.y * w.y + t4.z * w.z + t4.w * w.w;
                w = *(const float4*)&w_s[jgc * 324 + 2 * 64 + kk];
                ac2 += t4.x * w.x + t4.y * w.y + t4.z * w.z + t4.w * w.w;
                w = *(const float4*)&w_s[jgc * 324 + 3 * 64 + kk];
                ac3 += t4.x * w.x + t4.y * w.y + t4.z * w.z + t4.w * w.w;
                w = *(const float4*)&w_s[jgc * 324 + 4 * 64 + kk];
                ac4 += t4.x * w.x + t4.y * w.y + t4.z * w.z + t4.w * w.w;
            }
            __syncthreads();
        }
        if (kh == 1) {
            float* d = &shg[(rl * 16 + jgc) * 6];
            d[0] = ac0; d[1] = ac1; d[2] = ac2; d[3] = ac3; d[4] = ac4;
        }
        __syncthreads();
        if (kh == 0) {
            const float* dsh = &shg[(rl * 16 + jgc) * 6];
            ac0 += dsh[0]; ac1 += dsh[1]; ac2 += dsh[2]; ac3 += dsh[3]; ac4 += dsh[4];
            const int row = r0 + rl, j = jqb + jgc;
            const int dd = dec_s[rl];
            const int spc = dd & 63, blc = (dd >> 6) & 63;
            const bool shvc = (dd >> 12) & 1, rdvc = (dd >> 13) & 1;
            const int spn = spc + (shvc ? 1 : 0) - (rdvc ? 1 : 0);
            const int bln = blc - (shvc ? 1 : 0);
            float* stk = stack + (size_t)row * CAP * 1024;
            float* Xb = X + (size_t)row * XW;
            const float* bt = buffers + ((size_t)row * 40 + blc - 1) * 1024;
            float h;
            if (rdvc) {
                float a  = b_left[j] + ac0,        ii = b_left[512 + j] + ac1;
                float f1 = b_left[1024 + j] + ac2, f2 = b_left[1536 + j] + ac3;
                float oo = b_left[2048 + j] + ac4;
                const float* lp = lpart + (size_t)row * 2560;
#pragma unroll
                for (int kc = 0; kc < LSPLIT; kc++) {
                    const float* p = lp + (size_t)kc * 327680;
                    a += cload(p + j); ii += cload(p + 512 + j); f1 += cload(p + 1024 + j);
                    f2 += cload(p + 1536 + j); oo += cload(p + 2048 + j);
                }
                float s1c = stk[(size_t)(spc - 1) * 1024 + 512 + j];
                float s2c = stk[(size_t)(spc - 2) * 1024 + 512 + j];
                float cc = tanhf(a) * sigm(ii) + sigm(f1) * s2c + sigm(f2) * s1c;
                h = sigm(oo) * tanhf(cc);
                stk[(size_t)(spc - 2) * 1024 + j] = h;
                stk[(size_t)(spc - 2) * 1024 + 512 + j] = cc;
            } else if (shvc) {
                h = bt[j];
            } else {
                h = stk[(size_t)(spc - 1) * 1024 + j];
            }
            cstore(Xb + 512 + j, h);
            if (shvc) {
                stk[(size_t)spc * 1024 + j] = bt[j];
                stk[(size_t)spc * 1024 + 512 + j] = bt[512 + j];
            }
            cstore(Xb + j, buffers[((size_t)row * 40 + bln - 1) * 1024 + j]);
            cstore(Xb + 1024 + j, stk[(size_t)(spn - 2) * 1024 + j]);
        }
        __syncthreads();
        if (tid == 0) {
            bar_arrive(cnt + 448 + (bid >> 6) * 16, 64u, cnt + 32, ep);
            bar_wait(cnt + 32, 8u * ep);
        }
        __syncthreads();
    }
}

// ---------------- host ----------------
extern "C" void kernel_launch(void* const* d_in, const int* in_sizes, int n_in,
                              void* d_out, int out_size, void* d_ws, size_t ws_size,
                              hipStream_t stream) {
    const float* buffers = (const float*)d_in[0];
    const float* W_left  = (const float*)d_in[1];
    const float* b_left  = (const float*)d_in[2];
    const float* W_right = (const float*)d_in[3];
    const float* W_track = (const float*)d_in[4];
    const float* W_ih    = (const float*)d_in[5];
    const float* W_hh    = (const float*)d_in[6];
    const float* b_ih    = (const float*)d_in[7];
    const float* b_hh    = (const float*)d_in[8];
    const float* W_trans = (const float*)d_in[9];
    const float* b_trans = (const float*)d_in[10];
    float* out = (float*)d_out;

    float* ws = (float*)d_ws;
    size_t off = 0;
    float* W1T   = ws + off; off += 1792ull * 1024;             // 1,835,008
    float* W2T   = ws + off; off += 1024ull * 2560;             // 2,621,440
    float* W3T   = ws + off; off += 256ull * 2560;              //   655,360
    float* b1    = ws + off; off += 1024;
    float* X     = ws + off; off += (size_t)B_ * XW;            //   262,144
    float* TH    = ws + off; off += (size_t)B_ * 256;
    float* gpart = ws + off; off += (size_t)GSPLIT * B_ * 1024; // 1,835,008
    float* lpart = ws + off; off += (size_t)LSPLIT * B_ * 2560; // 2,621,440
    float* stack = ws + off; off += (size_t)B_ * CAP * 1024;    // 5,505,024
    int*   dec   = (int*)(ws + off); off += 128;
    unsigned* cnt = (unsigned*)(ws + off); off += 1024;

    {
        size_t total = 1792ull * 1024 + 1024ull * 2560 + 256ull * 2560 + 1024;
        int blocks = (int)((total + 255) / 256);
        k_repack<<<blocks, 256, 0, stream>>>(W_ih, W_hh, W_left, W_right, W_track, b_ih, b_hh,
                                             W1T, W2T, W3T, b1);
        k_init<<<B_, 256, 0, stream>>>(buffers, stack, X, cnt);
    }

    k_spinn<<<512, 256, 0, stream>>>(X, W1T, W2T, W3T, gpart, lpart, b1, b_left,
                                     W_trans, b_trans, buffers, stack, TH, dec, out, cnt);
    (void)in_sizes; (void)n_in; (void)out_size; (void)ws_size;
}

// Round 5
// 2803.434 us; speedup vs baseline: 1.5816x; 1.5816x over previous
//
#include <hip/hip_runtime.h>
#include <math.h>

// SPINN forward, fp32 throughout (argmax trajectory sensitivity forbids bf16/f16).
// 2 launches/step (round-1 champion structure; persistent kernels lose on this chip):
//   A (k_gemm, 544 blk): fused GEMM [gates || lstm5-sub], k-split partials
//   B (k_B, 512 blk = row x 4 j-slices): gates-reduce + LSTM + argmax + track-GEMM
//     (kh-split, both half-waves) + TreeLSTM node + stack + next-X
// mode 1 (ws permitting): 128-wide n-tiles, acc 8x8, KS=64 -> 0.5 B/FLOP LDS (fixes
//   LDS-BW bound of 64-wide/acc8x4 = 0.75 B/FLOP). mode 0: champion tiling (fits 61 MB).

#define B_ 128
#define CAP 40
#define XW 1792   // X row: [buf_h 0:512 | s1_h 512:1024 | s2_h 1024:1536 | th_old 1536:1792]
#define NSTEP 64

__device__ __forceinline__ float sigm(float x) { return 1.f / (1.f + expf(-x)); }

// ---------------- repack weights ----------------
// W1T[k][n], k in [0,1792): k<1536 -> W_ih[n][k], else W_hh[n][k-1536].       N=1024
// W2T[k][n], k in [0,1024): k<512 -> W_right[n][k] (s1h), else W_left[n][k-512] (s2h). N=2560
// W3T[k][n], k in [0,256):  W_track[n][k].                                    N=2560
__global__ void k_repack(const float* __restrict__ W_ih, const float* __restrict__ W_hh,
                         const float* __restrict__ W_left, const float* __restrict__ W_right,
                         const float* __restrict__ W_track, const float* __restrict__ b_ih,
                         const float* __restrict__ b_hh,
                         float* __restrict__ W1T, float* __restrict__ W2T,
                         float* __restrict__ W3T, float* __restrict__ b1) {
    size_t idx = (size_t)blockIdx.x * 256 + threadIdx.x;
    const size_t n1 = 1792ull * 1024ull;
    const size_t n2 = 1024ull * 2560ull;
    const size_t n3 = 256ull * 2560ull;
    if (idx < n1) {
        int k = (int)(idx >> 10), n = (int)(idx & 1023);
        W1T[idx] = (k < 1536) ? W_ih[(size_t)n * 1536 + k] : W_hh[(size_t)n * 256 + (k - 1536)];
    } else if (idx < n1 + n2) {
        size_t r = idx - n1;
        int k = (int)(r / 2560), n = (int)(r % 2560);
        W2T[r] = (k < 512) ? W_right[(size_t)n * 512 + k] : W_left[(size_t)n * 512 + (k - 512)];
    } else if (idx < n1 + n2 + n3) {
        size_t r = idx - n1 - n2;
        int k = (int)(r / 2560), n = (int)(r % 2560);
        W3T[r] = W_track[(size_t)n * 256 + k];
    } else if (idx < n1 + n2 + n3 + 1024) {
        int i = (int)(idx - n1 - n2 - n3);
        b1[i] = b_ih[i] + b_hh[i];
    }
}

// ---------------- init state ----------------
__global__ void k_init(const float* __restrict__ buffers, float* __restrict__ stack,
                       float* __restrict__ X, float* __restrict__ tc,
                       int* __restrict__ sptr, int* __restrict__ blen) {
    int b = blockIdx.x, t = threadIdx.x;
    const float* b0 = buffers + (size_t)b * 40 * 1024;      // buffers[b][0]
    const float* btop = b0 + 39 * 1024;                     // buffers[b][39]
    float* stk = stack + (size_t)b * CAP * 1024;
    for (int j = t; j < 1024; j += 256) { stk[j] = b0[j]; stk[1024 + j] = b0[j]; }
    float* Xb = X + (size_t)b * XW;
    for (int j = t; j < 512; j += 256) {
        Xb[j] = btop[j]; Xb[512 + j] = b0[j]; Xb[1024 + j] = b0[j];
    }
    Xb[1536 + t] = 0.f;           // th_old = 0
    tc[b * 256 + t] = 0.f;
    if (t == 0) { sptr[b] = 2; blen[b] = 40; }
}

// ---------------- A: fused tiled fp32 GEMM (gates || lstm5-sub), k-split partials ----
// mode 1: [0,224): gates ks=bid>>3 (28, KS=64), n0=(bid&7)*128; [224,544): lstm5
//         ks=tI/20 (16, KS=64), n0=(tI%20)*128. acc 8x8, 4 ds_read_b128 / 64 FMA.
// mode 0: [0,224): gates ks=bid>>4 (14, KS=128), n0=(bid&15)*64; [224,544): lstm5
//         ks=tI/40 (8, KS=128), n0=(tI%40)*64. acc 8x4 (champion).
__global__ __launch_bounds__(256, 3) void k_gemm(const float* __restrict__ X,
                                                 const float* __restrict__ W1T,
                                                 const float* __restrict__ W2T,
                                                 float* __restrict__ gpart,
                                                 float* __restrict__ lpart, int mode) {
    __shared__ float As[32][132];
    __shared__ float Ws[32][132];
    const int bid = blockIdx.x;
    const int tid = threadIdx.x;
    const int tm = tid >> 4, tn = tid & 15;

    if (mode) {
        const float* WT; float* out; int N, n0, k0, aoff;
        if (bid < 224) {
            int ks = bid >> 3, nb = bid & 7;
            WT = W1T; out = gpart + (size_t)ks * 131072;
            N = 1024; n0 = nb * 128; k0 = ks * 64; aoff = 0;
        } else {
            int tI = bid - 224; int ks = tI / 20, nb = tI % 20;
            WT = W2T; out = lpart + (size_t)ks * 327680;
            N = 2560; n0 = nb * 128; k0 = ks * 64; aoff = 512;
        }
        float acc[8][8];
#pragma unroll
        for (int i = 0; i < 8; i++)
#pragma unroll
            for (int j = 0; j < 8; j++) acc[i][j] = 0.f;

        for (int ki = 0; ki < 64; ki += 32) {
            const int kb = k0 + ki;
            __syncthreads();
            {   // stage A: As[kk][m] = X[m][aoff+kb+kk]
                int m = tid >> 1, c8 = (tid & 1) * 16;
                const float4* src = (const float4*)(X + (size_t)m * XW + aoff + kb + c8);
#pragma unroll
                for (int j = 0; j < 4; j++) {
                    float4 v = src[j];
                    int kk = c8 + j * 4;
                    As[kk + 0][m] = v.x; As[kk + 1][m] = v.y; As[kk + 2][m] = v.z; As[kk + 3][m] = v.w;
                }
            }
            {   // stage W: Ws[kk][c..c+15] = WT[kb+kk][n0+c..]
                int kk = tid >> 3, c = (tid & 7) * 16;
                const float4* src = (const float4*)(WT + (size_t)(kb + kk) * N + n0 + c);
                float4* dst = (float4*)(&Ws[kk][c]);
                dst[0] = src[0]; dst[1] = src[1]; dst[2] = src[2]; dst[3] = src[3];
            }
            __syncthreads();
#pragma unroll 4
            for (int kk = 0; kk < 32; kk++) {
                float a[8], w[8];
                *(float4*)&a[0] = *(const float4*)&As[kk][tm * 4];
                *(float4*)&a[4] = *(const float4*)&As[kk][64 + tm * 4];
                *(float4*)&w[0] = *(const float4*)&Ws[kk][tn * 4];
                *(float4*)&w[4] = *(const float4*)&Ws[kk][64 + tn * 4];
#pragma unroll
                for (int i = 0; i < 8; i++)
#pragma unroll
                    for (int j = 0; j < 8; j++) acc[i][j] += a[i] * w[j];
            }
        }
        float* base = out + n0;
#pragma unroll
        for (int i = 0; i < 8; i++) {
            int m = (i < 4) ? (tm * 4 + i) : (64 + tm * 4 + (i - 4));
            float* p = base + (size_t)m * N;
            *(float4*)(p + tn * 4) = make_float4(acc[i][0], acc[i][1], acc[i][2], acc[i][3]);
            *(float4*)(p + 64 + tn * 4) = make_float4(acc[i][4], acc[i][5], acc[i][6], acc[i][7]);
        }
    } else {
        const float* WT; float* out; int N, n0, k0, aoff;
        if (bid < 224) {
            int ks = bid >> 4, nb = bid & 15;
            WT = W1T; out = gpart + (size_t)ks * 131072;
            N = 1024; n0 = nb * 64; k0 = ks * 128; aoff = 0;
        } else {
            int tI = bid - 224; int ks = tI / 40, nb = tI % 40;
            WT = W2T; out = lpart + (size_t)ks * 327680;
            N = 2560; n0 = nb * 64; k0 = ks * 128; aoff = 512;
        }
        float acc[8][4];
#pragma unroll
        for (int i = 0; i < 8; i++)
#pragma unroll
            for (int j = 0; j < 4; j++) acc[i][j] = 0.f;

        for (int ki = 0; ki < 128; ki += 32) {
            const int kb = k0 + ki;
            __syncthreads();
            {   int m = tid >> 1, c8 = (tid & 1) * 16;
                const float4* src = (const float4*)(X + (size_t)m * XW + aoff + kb + c8);
#pragma unroll
                for (int j = 0; j < 4; j++) {
                    float4 v = src[j];
                    int kk = c8 + j * 4;
                    As[kk + 0][m] = v.x; As[kk + 1][m] = v.y; As[kk + 2][m] = v.z; As[kk + 3][m] = v.w;
                }
            }
            {   int kk = tid >> 3, c = (tid & 7) * 8;
                const float4* src = (const float4*)(WT + (size_t)(kb + kk) * N + n0 + c);
                float4* dst = (float4*)(&Ws[kk][c]);
                dst[0] = src[0]; dst[1] = src[1];
            }
            __syncthreads();
#pragma unroll 4
            for (int kk = 0; kk < 32; kk++) {
                float a[8], w[4];
                *(float4*)&a[0] = *(const float4*)&As[kk][tm * 4];
                *(float4*)&a[4] = *(const float4*)&As[kk][64 + tm * 4];
                *(float4*)&w[0] = *(const float4*)&Ws[kk][tn * 4];
#pragma unroll
                for (int i = 0; i < 8; i++)
#pragma unroll
                    for (int j = 0; j < 4; j++) acc[i][j] += a[i] * w[j];
            }
        }
        float* base = out + n0 + tn * 4;
#pragma unroll
        for (int i = 0; i < 8; i++) {
            int m = (i < 4) ? (tm * 4 + i) : (64 + tm * 4 + (i - 4));
            *(float4*)(base + (size_t)m * N) = make_float4(acc[i][0], acc[i][1], acc[i][2], acc[i][3]);
        }
    }
}

// ---------------- B: LSTM + argmax + track-GEMM (kh-split) + node + stack + next-X ----
// grid 512 = 128 rows x 4 j-slices (q). All 4 q-blocks of a row redundantly compute the
// LSTM/logits/argmax (deterministic, identical); slice work is split by q; within the
// track-GEMM both half-waves work (kh = t>>7 handles half the K range).
__global__ __launch_bounds__(256) void k_B(const float* __restrict__ gpart,
                                           const float* __restrict__ lpart,
                                           const float* __restrict__ b1,
                                           const float* __restrict__ b_left,
                                           const float* __restrict__ W3T,
                                           const float* __restrict__ W_trans,
                                           const float* __restrict__ b_trans,
                                           const float* __restrict__ buffers,
                                           float* __restrict__ stack,
                                           float* __restrict__ X,
                                           const float* __restrict__ tc_in,
                                           float* __restrict__ tc_out,
                                           const int* __restrict__ sp_in,
                                           int* __restrict__ sp_out,
                                           const int* __restrict__ bl_in,
                                           int* __restrict__ bl_out,
                                           float* __restrict__ out_s,
                                           int gsplit, int lsplit) {
    const int bid = blockIdx.x;
    const int b = bid >> 2, q = bid & 3;
    const int t = threadIdx.x;
    const int sp = sp_in[b], bl = bl_in[b];
    __shared__ float sh_th[256];
    __shared__ float redw[4][4];
    __shared__ float shg[5][128];

    // 1) gather gates partials + LSTM cell
    const float* gp = gpart + (size_t)b * 1024;
    float gi = b1[t], gf = b1[256 + t], gg = b1[512 + t], go = b1[768 + t];
#pragma unroll 4
    for (int kc = 0; kc < gsplit; kc++) {
        const float* p = gp + (size_t)kc * 131072;
        gi += p[t]; gf += p[256 + t]; gg += p[512 + t]; go += p[768 + t];
    }
    float tcv = tc_in[b * 256 + t];
    float tcn = sigm(gf) * tcv + sigm(gi) * tanhf(gg);
    float thn = sigm(go) * tanhf(tcn);
    if ((t >> 6) == q) tc_out[b * 256 + t] = tcn;
    sh_th[t] = thn;

    // 2) logits via wave shfl reduction + argmax (all threads identically)
    float v0 = thn * W_trans[t],       v1 = thn * W_trans[256 + t];
    float v2 = thn * W_trans[512 + t], v3 = thn * W_trans[768 + t];
#pragma unroll
    for (int off = 32; off > 0; off >>= 1) {
        v0 += __shfl_down(v0, off); v1 += __shfl_down(v1, off);
        v2 += __shfl_down(v2, off); v3 += __shfl_down(v3, off);
    }
    if ((t & 63) == 0) {
        int w = t >> 6;
        redw[w][0] = v0; redw[w][1] = v1; redw[w][2] = v2; redw[w][3] = v3;
    }
    __syncthreads();
    float lg0 = redw[0][0] + redw[1][0] + redw[2][0] + redw[3][0] + b_trans[0];
    float lg1 = redw[0][1] + redw[1][1] + redw[2][1] + redw[3][1] + b_trans[1];
    float lg2 = redw[0][2] + redw[1][2] + redw[2][2] + redw[3][2] + b_trans[2];
    float lg3 = redw[0][3] + redw[1][3] + redw[2][3] + redw[3][3] + b_trans[3];
    int tr = 0; float best = lg0;
    if (lg1 > best) { best = lg1; tr = 1; }
    if (lg2 > best) { best = lg2; tr = 2; }
    if (lg3 > best) { best = lg3; tr = 3; }
    const bool do_shift = (tr == 3) && (bl > 2);
    const bool do_red   = (tr == 2) && (sp > 3);
    const int spn = sp + (do_shift ? 1 : 0) - (do_red ? 1 : 0);
    const int bln = bl - (do_shift ? 1 : 0);
    if (q == 0 && t == 0) {
        out_s[b * 4 + 0] = lg0; out_s[b * 4 + 1] = lg1;
        out_s[b * 4 + 2] = lg2; out_s[b * 4 + 3] = lg3;
        sp_out[b] = spn; bl_out[b] = bln;
    }
    float* stk = stack + (size_t)b * CAP * 1024;

    // 3) reduce rows: lstm5 = sub-partials + b_left + W_track@th_new ; node.
    //    kh = t>>7: half-waves split the K range (128 each) and lsplit halves.
    const int jj = t & 127, kh = t >> 7, j = q * 128 + jj;
    float node_h = 0.f;
    float a, ii, f1, f2, oo;
    if (do_red) {
        if (kh == 0) {
            a  = b_left[j];        ii = b_left[512 + j]; f1 = b_left[1024 + j];
            f2 = b_left[1536 + j]; oo = b_left[2048 + j];
        } else { a = ii = f1 = f2 = oo = 0.f; }
        const float* lp = lpart + (size_t)b * 2560;
        const int half = lsplit >> 1;
        for (int kc = kh * half; kc < kh * half + half; kc++) {
            const float* p = lp + (size_t)kc * 327680;
            a += p[j]; ii += p[512 + j]; f1 += p[1024 + j]; f2 += p[1536 + j]; oo += p[2048 + j];
        }
        const float* w = W3T + j;
#pragma unroll 4
        for (int k = kh * 128; k < kh * 128 + 128; k++) {
            float th = sh_th[k];
            const float* wk = w + (size_t)k * 2560;
            a += th * wk[0]; ii += th * wk[512]; f1 += th * wk[1024];
            f2 += th * wk[1536]; oo += th * wk[2048];
        }
        if (kh == 1) {
            shg[0][jj] = a; shg[1][jj] = ii; shg[2][jj] = f1; shg[3][jj] = f2; shg[4][jj] = oo;
        }
    }
    __syncthreads();                       // do_red is block-uniform
    if (do_red && kh == 0) {
        a += shg[0][jj]; ii += shg[1][jj]; f1 += shg[2][jj];
        f2 += shg[3][jj]; oo += shg[4][jj];
        float s1c = stk[(size_t)(sp - 1) * 1024 + 512 + j];
        float s2c = stk[(size_t)(sp - 2) * 1024 + 512 + j];
        float c = tanhf(a) * sigm(ii) + sigm(f1) * s2c + sigm(f2) * s1c;
        float h = sigm(oo) * tanhf(c);
        stk[(size_t)(sp - 2) * 1024 + j] = h;          // own-slice addresses only
        stk[(size_t)(sp - 2) * 1024 + 512 + j] = c;
        node_h = h;
    }
    // 4) shift: push buf_top (slot sp untouched by any read this step)
    if (do_shift) {
        const float* bt = buffers + ((size_t)b * 40 + (bl - 1)) * 1024;
        const int idx = q * 256 + t;
        stk[(size_t)sp * 1024 + idx] = bt[idx];
    }
    // 5) build next X (slice j, kh==0 threads)
    float* Xb = X + (size_t)b * XW;
    if (kh == 0) {
        const float* btn = buffers + ((size_t)b * 40 + (bln - 1)) * 1024;
        Xb[j] = btn[j];                                 // buf_top' h
        float s1h;
        if (do_red)        s1h = node_h;                // just-built node (register)
        else if (do_shift) s1h = buffers[((size_t)b * 40 + (bl - 1)) * 1024 + j];
        else               s1h = stk[(size_t)(sp - 1) * 1024 + j];
        Xb[512 + j] = s1h;
        Xb[1024 + j] = stk[(size_t)(spn - 2) * 1024 + j];  // untouched slot in all 3 cases
    }
    if ((t >> 6) == q) Xb[1536 + t] = thn;              // th_old <- th_new, sliced by q
}

// ---------------- host ----------------
extern "C" void kernel_launch(void* const* d_in, const int* in_sizes, int n_in,
                              void* d_out, int out_size, void* d_ws, size_t ws_size,
                              hipStream_t stream) {
    const float* buffers = (const float*)d_in[0];
    const float* W_left  = (const float*)d_in[1];
    const float* b_left  = (const float*)d_in[2];
    const float* W_right = (const float*)d_in[3];
    const float* W_track = (const float*)d_in[4];
    const float* W_ih    = (const float*)d_in[5];
    const float* W_hh    = (const float*)d_in[6];
    const float* b_ih    = (const float*)d_in[7];
    const float* b_hh    = (const float*)d_in[8];
    const float* W_trans = (const float*)d_in[9];
    const float* b_trans = (const float*)d_in[10];
    float* out = (float*)d_out;

    float* ws = (float*)d_ws;
    size_t off = 0;
    float* W1T  = ws + off; off += 1792ull * 1024;             // 1,835,008
    float* W2T  = ws + off; off += 1024ull * 2560;             // 2,621,440
    float* W3T  = ws + off; off += 256ull * 2560;              //   655,360
    float* b1   = ws + off; off += 1024;
    float* X    = ws + off; off += (size_t)B_ * XW;            //   229,376
    float* tc_a = ws + off; off += (size_t)B_ * 256;
    float* tc_b = ws + off; off += (size_t)B_ * 256;

    // mode 1 (KS=64 tiles, GSPLIT=28/LSPLIT=16) needs ~78.3 MB; fall back if ws is short.
    size_t needA = (off + 28ull * 131072 + 16ull * 327680
                    + (size_t)B_ * CAP * 1024 + 512) * sizeof(float);
    const int mode   = (ws_size >= needA) ? 1 : 0;
    const int gsplit = mode ? 28 : 14;
    const int lsplit = mode ? 16 : 8;

    float* gpart = ws + off; off += (size_t)gsplit * 131072;
    float* lpart = ws + off; off += (size_t)lsplit * 327680;
    float* stack = ws + off; off += (size_t)B_ * CAP * 1024;   // 5,242,880
    int* sp_a = (int*)(ws + off); off += 128;
    int* sp_b = (int*)(ws + off); off += 128;
    int* bl_a = (int*)(ws + off); off += 128;
    int* bl_b = (int*)(ws + off); off += 128;

    {
        size_t total = 1792ull * 1024 + 1024ull * 2560 + 256ull * 2560 + 1024;
        int blocks = (int)((total + 255) / 256);
        k_repack<<<blocks, 256, 0, stream>>>(W_ih, W_hh, W_left, W_right, W_track, b_ih, b_hh,
                                             W1T, W2T, W3T, b1);
        k_init<<<B_, 256, 0, stream>>>(buffers, stack, X, tc_a, sp_a, bl_a);
    }

    for (int s = 0; s < NSTEP; s++) {
        k_gemm<<<544, 256, 0, stream>>>(X, W1T, W2T, gpart, lpart, mode);
        const float* tci = (s & 1) ? tc_b : tc_a;  float* tco = (s & 1) ? tc_a : tc_b;
        const int*   spi = (s & 1) ? sp_b : sp_a;  int*   spo = (s & 1) ? sp_a : sp_b;
        const int*   bli = (s & 1) ? bl_b : bl_a;  int*   blo = (s & 1) ? bl_a : bl_b;
        k_B<<<512, 256, 0, stream>>>(gpart, lpart, b1, b_left, W3T, W_trans, b_trans,
                                     buffers, stack, X, tci, tco, spi, spo, bli, blo,
                                     out + (size_t)s * B_ * 4, gsplit, lsplit);
    }
    (void)in_sizes; (void)n_in; (void)out_size; (void)ws_size;
}

// Round 6
// 2471.972 us; speedup vs baseline: 1.7936x; 1.1341x over previous
//
#include <hip/hip_runtime.h>
#include <math.h>

// SPINN forward, fp32 throughout (argmax trajectory sensitivity forbids bf16/f16).
// 2 launches/step. Key change vs champion: gates GEMM drops the th@W_hh^T slice
// (computed in k_B where th_new is already in LDS, ping-ponged via hhpart), making
// k_gemm EXACTLY 512 uniform blocks (2/CU, no 3-block straggler CUs):
//   A (k_gemm, 512 blk): [0,192) gates-x 12 splits x 16 n-tiles (K=1536,N=1024)
//                        [192,512) lstm5  8 splits x 40 n-tiles (K=1024,N=2560)
//   B (k_B, 512 blk = row x 4 j-slices): gather(12+hh) + LSTM + argmax + hh-GEMM
//     (K=256,N=1024, for next step) + track-GEMM (kh-split) + node + stack + next-X

#define B_ 128
#define CAP 40
#define XW 1536   // X row: [buf_h 0:512 | s1_h 512:1024 | s2_h 1024:1536]
#define GSPLIT 12
#define LSPLIT 8
#define NSTEP 64

__device__ __forceinline__ float sigm(float x) { return 1.f / (1.f + expf(-x)); }

// ---------------- repack weights ----------------
// W1T[k][n], k in [0,1536): W_ih[n][k].                                        N=1024
// W2T[k][n], k in [0,1024): k<512 -> W_right[n][k] (s1h), else W_left[n][k-512] (s2h). N=2560
// W3T[k][n], k in [0,256):  W_track[n][k].                                     N=2560
// WhhT[k][n], k in [0,256): W_hh[n][k].                                        N=1024
__global__ void k_repack(const float* __restrict__ W_ih, const float* __restrict__ W_hh,
                         const float* __restrict__ W_left, const float* __restrict__ W_right,
                         const float* __restrict__ W_track, const float* __restrict__ b_ih,
                         const float* __restrict__ b_hh,
                         float* __restrict__ W1T, float* __restrict__ W2T,
                         float* __restrict__ W3T, float* __restrict__ WhhT,
                         float* __restrict__ b1) {
    size_t idx = (size_t)blockIdx.x * 256 + threadIdx.x;
    const size_t n1 = 1536ull * 1024ull;   // 1,572,864
    const size_t n2 = 1024ull * 2560ull;   // 2,621,440
    const size_t n3 = 256ull * 2560ull;    //   655,360
    const size_t n4 = 256ull * 1024ull;    //   262,144
    if (idx < n1) {
        int k = (int)(idx >> 10), n = (int)(idx & 1023);
        W1T[idx] = W_ih[(size_t)n * 1536 + k];
    } else if (idx < n1 + n2) {
        size_t r = idx - n1;
        int k = (int)(r / 2560), n = (int)(r % 2560);
        W2T[r] = (k < 512) ? W_right[(size_t)n * 512 + k] : W_left[(size_t)n * 512 + (k - 512)];
    } else if (idx < n1 + n2 + n3) {
        size_t r = idx - n1 - n2;
        int k = (int)(r / 2560), n = (int)(r % 2560);
        W3T[r] = W_track[(size_t)n * 256 + k];
    } else if (idx < n1 + n2 + n3 + n4) {
        size_t r = idx - n1 - n2 - n3;
        int k = (int)(r >> 10), n = (int)(r & 1023);
        WhhT[r] = W_hh[(size_t)n * 256 + k];
    } else if (idx < n1 + n2 + n3 + n4 + 1024) {
        int i = (int)(idx - n1 - n2 - n3 - n4);
        b1[i] = b_ih[i] + b_hh[i];
    }
}

// ---------------- init state ----------------
__global__ void k_init(const float* __restrict__ buffers, float* __restrict__ stack,
                       float* __restrict__ X, float* __restrict__ tc,
                       float* __restrict__ hh,
                       int* __restrict__ sptr, int* __restrict__ blen) {
    int b = blockIdx.x, t = threadIdx.x;
    const float* b0 = buffers + (size_t)b * 40 * 1024;      // buffers[b][0]
    const float* btop = b0 + 39 * 1024;                     // buffers[b][39]
    float* stk = stack + (size_t)b * CAP * 1024;
    for (int j = t; j < 1024; j += 256) { stk[j] = b0[j]; stk[1024 + j] = b0[j]; }
    float* Xb = X + (size_t)b * XW;
    for (int j = t; j < 512; j += 256) {
        Xb[j] = btop[j]; Xb[512 + j] = b0[j]; Xb[1024 + j] = b0[j];
    }
    tc[b * 256 + t] = 0.f;
    for (int j = t; j < 1024; j += 256) hh[(size_t)b * 1024 + j] = 0.f;  // th0 = 0
    if (t == 0) { sptr[b] = 2; blen[b] = 40; }
}

// ---------------- A: fused tiled fp32 GEMM (gates-x || lstm5-sub), k-split partials --
// [0,192):  gates-x: ks=bid>>4 (12), n0=(bid&15)*64, K-chunk=[ks*128,+128), aoff=0
// [192,512): lstm5:  ks=tI/40  (8),  n0=(tI%40)*64,  K-chunk=[ks*128,+128), aoff=512
// per block: 128x64 output tile, 256 threads, acc 8x4, KT=32 inner staging.
__global__ __launch_bounds__(256, 3) void k_gemm(const float* __restrict__ X,
                                                 const float* __restrict__ W1T,
                                                 const float* __restrict__ W2T,
                                                 float* __restrict__ gpart,
                                                 float* __restrict__ lpart) {
    __shared__ float As[32][132];
    __shared__ float Ws[32][68];
    const int bid = blockIdx.x;
    const float* WT; float* out; int N, n0, k0, aoff;
    if (bid < 192) {
        int ks = bid >> 4, nb = bid & 15;
        WT = W1T; out = gpart + (size_t)ks * 131072;
        N = 1024; n0 = nb * 64; k0 = ks * 128; aoff = 0;
    } else {
        int tI = bid - 192; int ks = tI / 40, nb = tI % 40;
        WT = W2T; out = lpart + (size_t)ks * 327680;
        N = 2560; n0 = nb * 64; k0 = ks * 128; aoff = 512;
    }
    const int tid = threadIdx.x;
    const int tm = tid >> 4;      // 0..15
    const int tn = tid & 15;      // 0..15

    float acc[8][4];
#pragma unroll
    for (int i = 0; i < 8; i++)
#pragma unroll
        for (int j = 0; j < 4; j++) acc[i][j] = 0.f;

    for (int ki = 0; ki < 128; ki += 32) {
        const int kb = k0 + ki;
        __syncthreads();
        {   // stage A: As[kk][m] = X[m][aoff+kb+kk] ; 2 threads per row, 16 floats each
            int m = tid >> 1;
            int c8 = (tid & 1) * 16;
            const float4* src = (const float4*)(X + (size_t)m * XW + aoff + kb + c8);
#pragma unroll
            for (int j = 0; j < 4; j++) {
                float4 v = src[j];
                int kk = c8 + j * 4;
                As[kk + 0][m] = v.x; As[kk + 1][m] = v.y; As[kk + 2][m] = v.z; As[kk + 3][m] = v.w;
            }
        }
        {   // stage W: Ws[kk][c..c+7] = WT[kb+kk][n0+c..] ; 8 threads per k-row
            int kk = tid >> 3;
            int c = (tid & 7) * 8;
            const float4* src = (const float4*)(WT + (size_t)(kb + kk) * N + n0 + c);
            float4* dst = (float4*)(&Ws[kk][c]);
            dst[0] = src[0]; dst[1] = src[1];
        }
        __syncthreads();
#pragma unroll 4
        for (int kk = 0; kk < 32; kk++) {
            float a[8], w[4];
            *(float4*)&a[0] = *(const float4*)&As[kk][tm * 4];
            *(float4*)&a[4] = *(const float4*)&As[kk][64 + tm * 4];
            *(float4*)&w[0] = *(const float4*)&Ws[kk][tn * 4];
#pragma unroll
            for (int i = 0; i < 8; i++)
#pragma unroll
                for (int j = 0; j < 4; j++) acc[i][j] += a[i] * w[j];
        }
    }
    float* base = out + n0 + tn * 4;
#pragma unroll
    for (int i = 0; i < 8; i++) {
        int m = (i < 4) ? (tm * 4 + i) : (64 + tm * 4 + (i - 4));
        *(float4*)(base + (size_t)m * N) = make_float4(acc[i][0], acc[i][1], acc[i][2], acc[i][3]);
    }
}

// ---------------- B: LSTM + argmax + hh-GEMM + track-GEMM + node + stack + next-X ----
// grid 512 = 128 rows x 4 j-slices (q). All 4 q-blocks of a row redundantly compute the
// LSTM/logits/argmax (deterministic, identical); slice work is split by q.
__global__ __launch_bounds__(256) void k_B(const float* __restrict__ gpart,
                                           const float* __restrict__ lpart,
                                           const float* __restrict__ hh_in,
                                           float* __restrict__ hh_out,
                                           const float* __restrict__ b1,
                                           const float* __restrict__ b_left,
                                           const float* __restrict__ W3T,
                                           const float* __restrict__ WhhT,
                                           const float* __restrict__ W_trans,
                                           const float* __restrict__ b_trans,
                                           const float* __restrict__ buffers,
                                           float* __restrict__ stack,
                                           float* __restrict__ X,
                                           const float* __restrict__ tc_in,
                                           float* __restrict__ tc_out,
                                           const int* __restrict__ sp_in,
                                           int* __restrict__ sp_out,
                                           const int* __restrict__ bl_in,
                                           int* __restrict__ bl_out,
                                           float* __restrict__ out_s) {
    const int bid = blockIdx.x;
    const int b = bid >> 2, q = bid & 3;
    const int t = threadIdx.x;
    const int sp = sp_in[b], bl = bl_in[b];
    __shared__ float sh_th[256];
    __shared__ float redw[4][4];
    __shared__ float shg[5][128];

    // 1) gather gates partials (12 splits + hh lump) + LSTM cell
    const float* gp = gpart + (size_t)b * 1024;
    const float* hp = hh_in + (size_t)b * 1024;
    float gi = b1[t] + hp[t],             gf = b1[256 + t] + hp[256 + t];
    float gg = b1[512 + t] + hp[512 + t], go = b1[768 + t] + hp[768 + t];
#pragma unroll 4
    for (int kc = 0; kc < GSPLIT; kc++) {
        const float* p = gp + (size_t)kc * 131072;
        gi += p[t]; gf += p[256 + t]; gg += p[512 + t]; go += p[768 + t];
    }
    float tcv = tc_in[b * 256 + t];
    float tcn = sigm(gf) * tcv + sigm(gi) * tanhf(gg);
    float thn = sigm(go) * tanhf(tcn);
    if ((t >> 6) == q) tc_out[b * 256 + t] = tcn;
    sh_th[t] = thn;

    // 2) logits via wave shfl reduction + argmax (all threads identically)
    float v0 = thn * W_trans[t],       v1 = thn * W_trans[256 + t];
    float v2 = thn * W_trans[512 + t], v3 = thn * W_trans[768 + t];
#pragma unroll
    for (int off = 32; off > 0; off >>= 1) {
        v0 += __shfl_down(v0, off); v1 += __shfl_down(v1, off);
        v2 += __shfl_down(v2, off); v3 += __shfl_down(v3, off);
    }
    if ((t & 63) == 0) {
        int w = t >> 6;
        redw[w][0] = v0; redw[w][1] = v1; redw[w][2] = v2; redw[w][3] = v3;
    }
    __syncthreads();                       // redw + sh_th ready
    float lg0 = redw[0][0] + redw[1][0] + redw[2][0] + redw[3][0] + b_trans[0];
    float lg1 = redw[0][1] + redw[1][1] + redw[2][1] + redw[3][1] + b_trans[1];
    float lg2 = redw[0][2] + redw[1][2] + redw[2][2] + redw[3][2] + b_trans[2];
    float lg3 = redw[0][3] + redw[1][3] + redw[2][3] + redw[3][3] + b_trans[3];
    int tr = 0; float best = lg0;
    if (lg1 > best) { best = lg1; tr = 1; }
    if (lg2 > best) { best = lg2; tr = 2; }
    if (lg3 > best) { best = lg3; tr = 3; }
    const bool do_shift = (tr == 3) && (bl > 2);
    const bool do_red   = (tr == 2) && (sp > 3);
    const int spn = sp + (do_shift ? 1 : 0) - (do_red ? 1 : 0);
    const int bln = bl - (do_shift ? 1 : 0);
    if (q == 0 && t == 0) {
        out_s[b * 4 + 0] = lg0; out_s[b * 4 + 1] = lg1;
        out_s[b * 4 + 2] = lg2; out_s[b * 4 + 3] = lg3;
        sp_out[b] = spn; bl_out[b] = bln;
    }
    float* stk = stack + (size_t)b * CAP * 1024;

    // 3) hh-GEMM for NEXT step's gates: hh_out[b][q*256+t] = sum_k th[k]*WhhT[k][n]
    {
        const float* wh = WhhT + q * 256 + t;
        float h0 = 0, h1 = 0, h2 = 0, h3 = 0;
#pragma unroll 8
        for (int k = 0; k < 256; k += 4) {
            h0 += sh_th[k]     * wh[(size_t)k * 1024];
            h1 += sh_th[k + 1] * wh[(size_t)(k + 1) * 1024];
            h2 += sh_th[k + 2] * wh[(size_t)(k + 2) * 1024];
            h3 += sh_th[k + 3] * wh[(size_t)(k + 3) * 1024];
        }
        hh_out[(size_t)b * 1024 + q * 256 + t] = (h0 + h1) + (h2 + h3);
    }

    // 4) reduce rows: lstm5 = sub-partials + b_left + W_track@th_new ; node.
    //    kh = t>>7: half-waves split the K range (128 each) and lsplit halves.
    const int jj = t & 127, kh = t >> 7, j = q * 128 + jj;
    float node_h = 0.f;
    float a, ii, f1, f2, oo;
    if (do_red) {
        if (kh == 0) {
            a  = b_left[j];        ii = b_left[512 + j]; f1 = b_left[1024 + j];
            f2 = b_left[1536 + j]; oo = b_left[2048 + j];
        } else { a = ii = f1 = f2 = oo = 0.f; }
        const float* lp = lpart + (size_t)b * 2560;
        const int half = LSPLIT >> 1;
        for (int kc = kh * half; kc < kh * half + half; kc++) {
            const float* p = lp + (size_t)kc * 327680;
            a += p[j]; ii += p[512 + j]; f1 += p[1024 + j]; f2 += p[1536 + j]; oo += p[2048 + j];
        }
        const float* w = W3T + j;
#pragma unroll 4
        for (int k = kh * 128; k < kh * 128 + 128; k++) {
            float th = sh_th[k];
            const float* wk = w + (size_t)k * 2560;
            a += th * wk[0]; ii += th * wk[512]; f1 += th * wk[1024];
            f2 += th * wk[1536]; oo += th * wk[2048];
        }
        if (kh == 1) {
            shg[0][jj] = a; shg[1][jj] = ii; shg[2][jj] = f1; shg[3][jj] = f2; shg[4][jj] = oo;
        }
    }
    __syncthreads();                       // do_red is block-uniform
    if (do_red && kh == 0) {
        a += shg[0][jj]; ii += shg[1][jj]; f1 += shg[2][jj];
        f2 += shg[3][jj]; oo += shg[4][jj];
        float s1c = stk[(size_t)(sp - 1) * 1024 + 512 + j];
        float s2c = stk[(size_t)(sp - 2) * 1024 + 512 + j];
        float c = tanhf(a) * sigm(ii) + sigm(f1) * s2c + sigm(f2) * s1c;
        float h = sigm(oo) * tanhf(c);
        stk[(size_t)(sp - 2) * 1024 + j] = h;          // own-slice addresses only
        stk[(size_t)(sp - 2) * 1024 + 512 + j] = c;
        node_h = h;
    }
    // 5) shift: push buf_top (slot sp untouched by any read this step)
    if (do_shift) {
        const float* bt = buffers + ((size_t)b * 40 + (bl - 1)) * 1024;
        const int idx = q * 256 + t;
        stk[(size_t)sp * 1024 + idx] = bt[idx];
    }
    // 6) build next X (slice j, kh==0 threads)
    float* Xb = X + (size_t)b * XW;
    if (kh == 0) {
        const float* btn = buffers + ((size_t)b * 40 + (bln - 1)) * 1024;
        Xb[j] = btn[j];                                 // buf_top' h
        float s1h;
        if (do_red)        s1h = node_h;                // just-built node (register)
        else if (do_shift) s1h = buffers[((size_t)b * 40 + (bl - 1)) * 1024 + j];
        else               s1h = stk[(size_t)(sp - 1) * 1024 + j];
        Xb[512 + j] = s1h;
        Xb[1024 + j] = stk[(size_t)(spn - 2) * 1024 + j];  // untouched slot in all 3 cases
    }
}

// ---------------- host ----------------
extern "C" void kernel_launch(void* const* d_in, const int* in_sizes, int n_in,
                              void* d_out, int out_size, void* d_ws, size_t ws_size,
                              hipStream_t stream) {
    const float* buffers = (const float*)d_in[0];
    const float* W_left  = (const float*)d_in[1];
    const float* b_left  = (const float*)d_in[2];
    const float* W_right = (const float*)d_in[3];
    const float* W_track = (const float*)d_in[4];
    const float* W_ih    = (const float*)d_in[5];
    const float* W_hh    = (const float*)d_in[6];
    const float* b_ih    = (const float*)d_in[7];
    const float* b_hh    = (const float*)d_in[8];
    const float* W_trans = (const float*)d_in[9];
    const float* b_trans = (const float*)d_in[10];
    float* out = (float*)d_out;

    float* ws = (float*)d_ws;
    size_t off = 0;
    float* W1T   = ws + off; off += 1536ull * 1024;             // 1,572,864
    float* W2T   = ws + off; off += 1024ull * 2560;             // 2,621,440
    float* W3T   = ws + off; off += 256ull * 2560;              //   655,360
    float* WhhT  = ws + off; off += 256ull * 1024;              //   262,144
    float* b1    = ws + off; off += 1024;
    float* X     = ws + off; off += (size_t)B_ * XW;            //   196,608
    float* tc_a  = ws + off; off += (size_t)B_ * 256;
    float* tc_b  = ws + off; off += (size_t)B_ * 256;
    float* hh_a  = ws + off; off += (size_t)B_ * 1024;          //   131,072
    float* hh_b  = ws + off; off += (size_t)B_ * 1024;
    float* gpart = ws + off; off += (size_t)GSPLIT * 131072;    // 1,572,864
    float* lpart = ws + off; off += (size_t)LSPLIT * 327680;    // 2,621,440
    float* stack = ws + off; off += (size_t)B_ * CAP * 1024;    // 5,242,880
    int* sp_a = (int*)(ws + off); off += 128;
    int* sp_b = (int*)(ws + off); off += 128;
    int* bl_a = (int*)(ws + off); off += 128;
    int* bl_b = (int*)(ws + off); off += 128;

    {
        size_t total = 1536ull * 1024 + 1024ull * 2560 + 256ull * 2560 + 256ull * 1024 + 1024;
        int blocks = (int)((total + 255) / 256);
        k_repack<<<blocks, 256, 0, stream>>>(W_ih, W_hh, W_left, W_right, W_track, b_ih, b_hh,
                                             W1T, W2T, W3T, WhhT, b1);
        k_init<<<B_, 256, 0, stream>>>(buffers, stack, X, tc_a, hh_a, sp_a, bl_a);
    }

    for (int s = 0; s < NSTEP; s++) {
        k_gemm<<<512, 256, 0, stream>>>(X, W1T, W2T, gpart, lpart);
        const float* tci = (s & 1) ? tc_b : tc_a;  float* tco = (s & 1) ? tc_a : tc_b;
        const float* hhi = (s & 1) ? hh_b : hh_a;  float* hho = (s & 1) ? hh_a : hh_b;
        const int*   spi = (s & 1) ? sp_b : sp_a;  int*   spo = (s & 1) ? sp_a : sp_b;
        const int*   bli = (s & 1) ? bl_b : bl_a;  int*   blo = (s & 1) ? bl_a : bl_b;
        k_B<<<512, 256, 0, stream>>>(gpart, lpart, hhi, hho, b1, b_left, W3T, WhhT,
                                     W_trans, b_trans, buffers, stack, X, tci, tco,
                                     spi, spo, bli, blo, out + (size_t)s * B_ * 4);
    }
    (void)in_sizes; (void)n_in; (void)out_size; (void)ws_size;
}